// Round 1
// baseline (4202.545 us; speedup 1.0000x reference)
//
#include <hip/hip_runtime.h>
#include <math.h>

#define N_LIGC 1024
#define N_PROTC 8192
#define NTOT 9216
#define KNN 48
#define HID 256
#define DEPTHC 5
#define ETOT (N_LIGC*KNN)

__device__ __forceinline__ float freq_f(int i){
  double p = (double)(1 << (2*i));
  return (float)((2.0*3.14159265358979323846)*p/15.0);
}
__device__ __forceinline__ float silu_f(float v){ return v/(1.0f+expf(-v)); }

// ---------------- feature embedding + coords ----------------
__global__ __launch_bounds__(256) void k_embed(
    const float* __restrict__ protPos, const int* __restrict__ protEle,
    const int* __restrict__ protAA, const int* __restrict__ protBB,
    const float* __restrict__ XtPos, const float* __restrict__ XtFeat,
    const int* __restrict__ tArr, const float* __restrict__ WtTime,
    const float* __restrict__ Wele, const float* __restrict__ Waa,
    const float* __restrict__ Wbb,
    float* __restrict__ feats, float* __restrict__ X0, float* __restrict__ X1)
{
  int i = blockIdx.x*256+threadIdx.x;
  if (i >= NTOT) return;
  float c0,c1,c2;
  float* f = feats + i*40;
  if (i < N_LIGC){
    c0 = XtPos[i*3+0]; c1 = XtPos[i*3+1]; c2 = XtPos[i*3+2];
    #pragma unroll
    for (int k=0;k<32;k++) f[k] = XtFeat[i*32+k];
    int tt = tArr[i];
    #pragma unroll
    for (int k=0;k<8;k++) f[32+k] = WtTime[tt*8+k];
  } else {
    int p = i - N_LIGC;
    c0 = protPos[p*3+0]; c1 = protPos[p*3+1]; c2 = protPos[p*3+2];
    int e = protEle[p], a = protAA[p], b = protBB[p];
    #pragma unroll
    for (int k=0;k<16;k++) f[k] = Wele[e*16+k];
    #pragma unroll
    for (int k=0;k<16;k++) f[16+k] = Waa[a*16+k];
    #pragma unroll
    for (int k=0;k<8;k++) f[32+k] = Wbb[b*8+k];
  }
  X0[i*3+0]=c0; X0[i*3+1]=c1; X0[i*3+2]=c2;
  X1[i*3+0]=c0; X1[i*3+1]=c1; X1[i*3+2]=c2;
}

// ---------------- h = feats @ W_in + b_in ----------------
__global__ __launch_bounds__(256) void k_hinit(const float* __restrict__ feats,
    const float* __restrict__ Win, const float* __restrict__ bin, float* __restrict__ h)
{
  __shared__ float sF[8*40];
  int blk=blockIdx.x, tid=threadIdx.x;
  int n0=blk*8;
  for (int x=tid;x<320;x+=256) sF[x]=feats[n0*40+x];
  __syncthreads();
  float acc[8];
  float b=bin[tid];
  #pragma unroll
  for (int n=0;n<8;n++) acc[n]=b;
  for (int k=0;k<40;k++){
    float w=Win[k*HID+tid];
    #pragma unroll
    for (int n=0;n<8;n++) acc[n]+=sF[n*40+k]*w;
  }
  #pragma unroll
  for (int n=0;n<8;n++) h[(n0+n)*HID+tid]=acc[n];
}

// ---------------- KNN: one block per ligand node ----------------
__global__ __launch_bounds__(256) void k_knn(const float* __restrict__ X,
    int* __restrict__ col, float* __restrict__ emb0)
{
  __shared__ float sd[NTOT];
  __shared__ float selD[KNN];
  __shared__ float rv[4];
  __shared__ int ri[4];
  int b = blockIdx.x, tid = threadIdx.x;
  float px = X[b*3+0], py = X[b*3+1], pz = X[b*3+2];
  for (int i=tid;i<NTOT;i+=256){
    float dx = px - X[i*3+0], dy = py - X[i*3+1], dz = pz - X[i*3+2];
    float d2 = dx*dx+dy*dy+dz*dz;
    sd[i] = (i==b) ? INFINITY : d2;
  }
  __syncthreads();
  for (int it=0; it<KNN; it++){
    float bv = INFINITY; int bi = 0x7fffffff;
    for (int i=tid;i<NTOT;i+=256){
      float v = sd[i];
      if (v < bv){ bv=v; bi=i; }      // strict < keeps lowest index on ties
    }
    #pragma unroll
    for (int off=32; off>=1; off>>=1){
      float ov = __shfl_down(bv, off);
      int   oi = __shfl_down(bi, off);
      if (ov < bv || (ov==bv && oi<bi)){ bv=ov; bi=oi; }
    }
    if ((tid&63)==0){ rv[tid>>6]=bv; ri[tid>>6]=bi; }
    __syncthreads();
    if (tid==0){
      for (int w=1;w<4;w++){
        if (rv[w]<bv || (rv[w]==bv && ri[w]<bi)){ bv=rv[w]; bi=ri[w]; }
      }
      col[b*KNN+it] = bi;
      selD[it] = bv;
      sd[bi] = INFINITY;
    }
    __syncthreads();
  }
  if (tid < KNN){
    float d = sqrtf(selD[tid] + 1e-8f);
    int base = (b*KNN+tid)*12;
    #pragma unroll
    for (int i=0;i<6;i++){
      float fr = freq_f(i);
      emb0[base+i]   = sinf(d*fr);
      emb0[base+6+i] = cosf(d*fr);
    }
  }
}

// ---------------- edge MLP + attention gate + partial aggregate ----------------
// block = 24 edges (half of one ligand row). 2048 blocks.
__global__ __launch_bounds__(256) void k_edge(
    const float* __restrict__ h, const float* __restrict__ xc,
    const int* __restrict__ colIdx, const float* __restrict__ emb0,
    const float* __restrict__ eW1, const float* __restrict__ eB1,
    const float* __restrict__ eW2, const float* __restrict__ eB2,
    const float* __restrict__ attW, const float* __restrict__ attB,
    float* __restrict__ aggP, int l)
{
  __shared__ __align__(16) float sB[24*280];   // stage1 per-edge input; reused as m1 (24*256)
  __shared__ __align__(16) float sHrow[256];
  __shared__ float sSig[24];
  __shared__ int sCol[24];
  int blk=blockIdx.x, tid=threadIdx.x;
  int row=blk>>1, e0=blk*24;
  if (tid<24) sCol[tid]=colIdx[e0+tid];
  sHrow[tid]=h[row*HID+tid];
  __syncthreads();
  #pragma unroll
  for (int e=0;e<24;e++) sB[e*280+tid] = h[sCol[e]*HID+tid];
  if (tid<24){
    int cg = sCol[tid];
    float dx = xc[row*3+0]-xc[cg*3+0];
    float dy = xc[row*3+1]-xc[cg*3+1];
    float dz = xc[row*3+2]-xc[cg*3+2];
    float d2 = dx*dx+dy*dy+dz*dz;
    float d = sqrtf(d2+1e-8f);
    #pragma unroll
    for (int i=0;i<6;i++){
      float fr=freq_f(i);
      sB[tid*280+256+i] = sinf(d*fr);
      sB[tid*280+262+i] = cosf(d*fr);
    }
    #pragma unroll
    for (int i=0;i<12;i++) sB[tid*280+268+i] = emb0[(e0+tid)*12+i];
  }
  __syncthreads();
  const float* W1 = eW1 + l*536*HID;
  float base = eB1[l*HID+tid];
  const float4* sH4 = (const float4*)sHrow;
  #pragma unroll 2
  for (int k4=0;k4<64;k4++){
    float4 hr = sH4[k4];
    base += hr.x*W1[(4*k4+0)*HID+tid];
    base += hr.y*W1[(4*k4+1)*HID+tid];
    base += hr.z*W1[(4*k4+2)*HID+tid];
    base += hr.w*W1[(4*k4+3)*HID+tid];
  }
  float acc[24];
  #pragma unroll
  for (int e=0;e<24;e++) acc[e]=0.f;
  const float* W1b = W1 + 256*HID;
  const float4* sB4 = (const float4*)sB;
  #pragma unroll 2
  for (int k4=0;k4<70;k4++){
    float w0=W1b[(4*k4+0)*HID+tid];
    float w1=W1b[(4*k4+1)*HID+tid];
    float w2=W1b[(4*k4+2)*HID+tid];
    float w3=W1b[(4*k4+3)*HID+tid];
    #pragma unroll
    for (int e=0;e<24;e++){
      float4 a = sB4[e*70+k4];
      acc[e] += a.x*w0 + a.y*w1 + a.z*w2 + a.w*w3;
    }
  }
  __syncthreads();
  #pragma unroll
  for (int e=0;e<24;e++) sB[e*HID+tid] = silu_f(base+acc[e]);
  __syncthreads();
  const float* W2 = eW2 + l*HID*HID;
  float b2 = eB2[l*HID+tid];
  float acc2[24];
  #pragma unroll
  for (int e=0;e<24;e++) acc2[e]=b2;
  #pragma unroll 2
  for (int k4=0;k4<64;k4++){
    float w0=W2[(4*k4+0)*HID+tid];
    float w1=W2[(4*k4+1)*HID+tid];
    float w2=W2[(4*k4+2)*HID+tid];
    float w3=W2[(4*k4+3)*HID+tid];
    #pragma unroll
    for (int e=0;e<24;e++){
      float4 a = sB4[e*64+k4];
      acc2[e] += a.x*w0 + a.y*w1 + a.z*w2 + a.w*w3;
    }
  }
  float m2[24];
  #pragma unroll
  for (int e=0;e<24;e++) m2[e]=silu_f(acc2[e]);
  __syncthreads();
  float aw = attW[l*HID+tid];
  #pragma unroll
  for (int e=0;e<24;e++) sB[e*HID+tid] = m2[e]*aw;
  __syncthreads();
  if (tid<24){
    float s=0.f;
    #pragma unroll 4
    for (int j4=0;j4<64;j4++){ float4 v=sB4[tid*64+j4]; s+=v.x+v.y+v.z+v.w; }
    s += attB[l];
    sSig[tid]=1.f/(1.f+expf(-s));
  }
  __syncthreads();
  float agg=0.f;
  #pragma unroll
  for (int e=0;e<24;e++) agg += m2[e]*sSig[e];
  aggP[blk*HID+tid]=agg;
}

// ---------------- node MLP (residual) ----------------
__global__ __launch_bounds__(256) void k_node(
    float* __restrict__ h, const float* __restrict__ aggP,
    const float* __restrict__ nW1, const float* __restrict__ nB1,
    const float* __restrict__ nW2, const float* __restrict__ nB2, int l)
{
  __shared__ __align__(16) float sIn[16*512];
  int blk=blockIdx.x, tid=threadIdx.x;
  int n0=blk*16;
  float hreg[16];
  #pragma unroll
  for (int n=0;n<16;n++){
    int node=n0+n;
    float hv = h[node*HID+tid];
    hreg[n]=hv;
    sIn[n*512+tid]=hv;
    float ag = 0.f;
    if (node < N_LIGC)
      ag = (aggP[(2*node)*HID+tid] + aggP[(2*node+1)*HID+tid]) / 5.0f;
    sIn[n*512+256+tid]=ag;
  }
  __syncthreads();
  const float* W1 = nW1 + l*512*HID;
  float b1 = nB1[l*HID+tid];
  float accU[16];
  #pragma unroll
  for (int n=0;n<16;n++) accU[n]=b1;
  const float4* s4=(const float4*)sIn;
  #pragma unroll 2
  for (int k4=0;k4<128;k4++){
    float w0=W1[(4*k4+0)*HID+tid];
    float w1=W1[(4*k4+1)*HID+tid];
    float w2=W1[(4*k4+2)*HID+tid];
    float w3=W1[(4*k4+3)*HID+tid];
    #pragma unroll
    for (int n=0;n<16;n++){
      float4 a=s4[n*128+k4];
      accU[n]+=a.x*w0+a.y*w1+a.z*w2+a.w*w3;
    }
  }
  __syncthreads();
  #pragma unroll
  for (int n=0;n<16;n++) sIn[n*HID+tid]=silu_f(accU[n]);
  __syncthreads();
  const float* W2=nW2+l*HID*HID;
  float b2=nB2[l*HID+tid];
  float acc2[16];
  #pragma unroll
  for (int n=0;n<16;n++) acc2[n]=b2;
  #pragma unroll 2
  for (int k4=0;k4<64;k4++){
    float w0=W2[(4*k4+0)*HID+tid];
    float w1=W2[(4*k4+1)*HID+tid];
    float w2=W2[(4*k4+2)*HID+tid];
    float w3=W2[(4*k4+3)*HID+tid];
    #pragma unroll
    for (int n=0;n<16;n++){
      float4 a=s4[n*64+k4];
      acc2[n]+=a.x*w0+a.y*w1+a.z*w2+a.w*w3;
    }
  }
  #pragma unroll
  for (int n=0;n<16;n++) h[(n0+n)*HID+tid]=hreg[n]+acc2[n];
}

// ---------------- coord MLP (uses UPDATED h) + partial x contribution ----------------
__global__ __launch_bounds__(256) void k_coord(
    const float* __restrict__ h, const float* __restrict__ xc,
    const int* __restrict__ colIdx, const float* __restrict__ emb0,
    const float* __restrict__ cW1, const float* __restrict__ cB1,
    const float* __restrict__ cW2, const float* __restrict__ cB2,
    const float* __restrict__ cW3,
    float* __restrict__ xP, int l)
{
  __shared__ __align__(16) float sB[24*280];
  __shared__ __align__(16) float sHrow[256];
  __shared__ float sS[24];
  __shared__ float sCd[24*3];
  __shared__ int sCol[24];
  int blk=blockIdx.x, tid=threadIdx.x;
  int row=blk>>1, e0=blk*24;
  if (tid<24) sCol[tid]=colIdx[e0+tid];
  sHrow[tid]=h[row*HID+tid];
  __syncthreads();
  #pragma unroll
  for (int e=0;e<24;e++) sB[e*280+tid] = h[sCol[e]*HID+tid];
  if (tid<24){
    int cg = sCol[tid];
    float dx = xc[row*3+0]-xc[cg*3+0];
    float dy = xc[row*3+1]-xc[cg*3+1];
    float dz = xc[row*3+2]-xc[cg*3+2];
    float d2 = dx*dx+dy*dy+dz*dz;
    float d = sqrtf(d2+1e-8f);
    float den = d + 1.0f;
    sCd[tid*3+0]=dx/den; sCd[tid*3+1]=dy/den; sCd[tid*3+2]=dz/den;
    #pragma unroll
    for (int i=0;i<6;i++){
      float fr=freq_f(i);
      sB[tid*280+256+i] = sinf(d*fr);
      sB[tid*280+262+i] = cosf(d*fr);
    }
    #pragma unroll
    for (int i=0;i<12;i++) sB[tid*280+268+i] = emb0[(e0+tid)*12+i];
  }
  __syncthreads();
  const float* W1 = cW1 + l*536*HID;
  float base = cB1[l*HID+tid];
  const float4* sH4 = (const float4*)sHrow;
  #pragma unroll 2
  for (int k4=0;k4<64;k4++){
    float4 hr = sH4[k4];
    base += hr.x*W1[(4*k4+0)*HID+tid];
    base += hr.y*W1[(4*k4+1)*HID+tid];
    base += hr.z*W1[(4*k4+2)*HID+tid];
    base += hr.w*W1[(4*k4+3)*HID+tid];
  }
  float acc[24];
  #pragma unroll
  for (int e=0;e<24;e++) acc[e]=0.f;
  const float* W1b = W1 + 256*HID;
  const float4* sB4 = (const float4*)sB;
  #pragma unroll 2
  for (int k4=0;k4<70;k4++){
    float w0=W1b[(4*k4+0)*HID+tid];
    float w1=W1b[(4*k4+1)*HID+tid];
    float w2=W1b[(4*k4+2)*HID+tid];
    float w3=W1b[(4*k4+3)*HID+tid];
    #pragma unroll
    for (int e=0;e<24;e++){
      float4 a = sB4[e*70+k4];
      acc[e] += a.x*w0 + a.y*w1 + a.z*w2 + a.w*w3;
    }
  }
  __syncthreads();
  #pragma unroll
  for (int e=0;e<24;e++) sB[e*HID+tid] = silu_f(base+acc[e]);
  __syncthreads();
  const float* W2 = cW2 + l*HID*HID;
  float b2 = cB2[l*HID+tid];
  float acc2[24];
  #pragma unroll
  for (int e=0;e<24;e++) acc2[e]=b2;
  #pragma unroll 2
  for (int k4=0;k4<64;k4++){
    float w0=W2[(4*k4+0)*HID+tid];
    float w1=W2[(4*k4+1)*HID+tid];
    float w2=W2[(4*k4+2)*HID+tid];
    float w3=W2[(4*k4+3)*HID+tid];
    #pragma unroll
    for (int e=0;e<24;e++){
      float4 a = sB4[e*64+k4];
      acc2[e] += a.x*w0 + a.y*w1 + a.z*w2 + a.w*w3;
    }
  }
  float c2r[24];
  #pragma unroll
  for (int e=0;e<24;e++) c2r[e]=silu_f(acc2[e]);
  __syncthreads();
  float w3r = cW3[l*HID+tid];
  #pragma unroll
  for (int e=0;e<24;e++) sB[e*HID+tid] = c2r[e]*w3r;
  __syncthreads();
  if (tid<24){
    float s=0.f;
    #pragma unroll 4
    for (int j4=0;j4<64;j4++){ float4 v=sB4[tid*64+j4]; s+=v.x+v.y+v.z+v.w; }
    sS[tid]=s;
  }
  __syncthreads();
  if (tid<3){
    float u=0.f;
    #pragma unroll
    for (int e=0;e<24;e++) u += sCd[e*3+tid]*sS[e];
    xP[blk*3+tid]=u;
  }
}

// ---------------- combine partial x updates (ligand rows only) ----------------
__global__ void k_xcomb(const float* __restrict__ xc, float* __restrict__ xn,
                        const float* __restrict__ xP)
{
  int i=threadIdx.x;  // 1024 threads
  #pragma unroll
  for (int c=0;c<3;c++)
    xn[i*3+c] = xc[i*3+c] + (xP[(2*i)*3+c]+xP[(2*i+1)*3+c])/5.0f;
}

// ---------------- outputs ----------------
__global__ void k_outx(const float* __restrict__ x, const float* __restrict__ posw,
                       float* __restrict__ out)
{
  int i=blockIdx.x*1024+threadIdx.x;
  if (i<3072) out[i]=x[i]*posw[0];
}

__global__ __launch_bounds__(256) void k_outh(const float* __restrict__ h,
    const float* __restrict__ Wout, const float* __restrict__ bout,
    float* __restrict__ out)
{
  __shared__ float sH[2048];
  int blk=blockIdx.x, tid=threadIdx.x;
  int n0=blk*8;
  for (int x=tid;x<2048;x+=256) sH[x]=h[n0*HID+x];
  __syncthreads();
  int nl=tid>>5, j=tid&31;
  float acc=bout[j];
  #pragma unroll 4
  for (int k=0;k<256;k++) acc += sH[nl*HID+k]*Wout[k*32+j];
  out[3072 + (n0+nl)*32 + j]=acc;
}

extern "C" void kernel_launch(void* const* d_in, const int* in_sizes, int n_in,
                              void* d_out, int out_size, void* d_ws, size_t ws_size,
                              hipStream_t stream)
{
  const float* protPos = (const float*)d_in[0];
  const int*   protEle = (const int*)d_in[1];
  const int*   protAA  = (const int*)d_in[2];
  const int*   protBB  = (const int*)d_in[3];
  const float* XtPos   = (const float*)d_in[4];
  const float* XtFeat  = (const float*)d_in[5];
  const int*   tArr    = (const int*)d_in[6];
  const float* WtTime  = (const float*)d_in[7];
  const float* Wele    = (const float*)d_in[8];
  const float* Waa     = (const float*)d_in[9];
  const float* Wbb     = (const float*)d_in[10];
  const float* Win     = (const float*)d_in[11];
  const float* bin     = (const float*)d_in[12];
  const float* Wout    = (const float*)d_in[13];
  const float* bout    = (const float*)d_in[14];
  const float* eW1     = (const float*)d_in[15];
  const float* eB1     = (const float*)d_in[16];
  const float* eW2     = (const float*)d_in[17];
  const float* eB2     = (const float*)d_in[18];
  const float* attW    = (const float*)d_in[19];
  const float* attB    = (const float*)d_in[20];
  const float* nW1     = (const float*)d_in[21];
  const float* nB1     = (const float*)d_in[22];
  const float* nW2     = (const float*)d_in[23];
  const float* nB2     = (const float*)d_in[24];
  const float* cW1     = (const float*)d_in[25];
  const float* cB1     = (const float*)d_in[26];
  const float* cW2     = (const float*)d_in[27];
  const float* cB2     = (const float*)d_in[28];
  const float* cW3     = (const float*)d_in[29];
  const float* posw    = (const float*)d_in[30];

  float* ws   = (float*)d_ws;
  float* X0   = ws;
  float* X1   = X0 + NTOT*3;
  float* feats= X1 + NTOT*3;
  float* h    = feats + NTOT*40;
  int*   col  = (int*)(h + NTOT*HID);
  float* emb0 = (float*)(col + ETOT);
  float* aggP = emb0 + ETOT*12;
  float* xP   = aggP + 2048*HID;

  k_embed<<<36,256,0,stream>>>(protPos,protEle,protAA,protBB,XtPos,XtFeat,tArr,
                               WtTime,Wele,Waa,Wbb,feats,X0,X1);
  k_hinit<<<NTOT/8,256,0,stream>>>(feats,Win,bin,h);
  k_knn<<<N_LIGC,256,0,stream>>>(X0,col,emb0);

  float* xc = X0; float* xn = X1;
  for (int l=0;l<DEPTHC;l++){
    k_edge<<<2048,256,0,stream>>>(h,xc,col,emb0,eW1,eB1,eW2,eB2,attW,attB,aggP,l);
    k_node<<<NTOT/16,256,0,stream>>>(h,aggP,nW1,nB1,nW2,nB2,l);
    k_coord<<<2048,256,0,stream>>>(h,xc,col,emb0,cW1,cB1,cW2,cB2,cW3,xP,l);
    k_xcomb<<<1,1024,0,stream>>>(xc,xn,xP);
    float* t2=xc; xc=xn; xn=t2;
  }
  k_outx<<<3,1024,0,stream>>>(xc,posw,(float*)d_out);
  k_outh<<<N_LIGC/8,256,0,stream>>>(h,Wout,bout,(float*)d_out);
}

// Round 2
// 916.669 us; speedup vs baseline: 4.5846x; 4.5846x over previous
//
#include <hip/hip_runtime.h>
#include <hip/hip_bf16.h>
#include <math.h>

#define N_LIGC 1024
#define NTOT 9216
#define KNN 48
#define HID 256
#define DEPTHC 5
#define ETOT (N_LIGC*KNN)

typedef unsigned short u16;
typedef __attribute__((ext_vector_type(8))) short bf16x8;
typedef __attribute__((ext_vector_type(4))) float f32x4;

__device__ __forceinline__ float freq_f(int i){
  double p = (double)(1 << (2*i));
  return (float)((2.0*3.14159265358979323846)*p/15.0);
}
__device__ __forceinline__ float silu_f(float v){ return v/(1.0f+expf(-v)); }
__device__ __forceinline__ u16 f2b(float f){
  union { __hip_bfloat16 h; u16 u; } c; c.h = __float2bfloat16(f); return c.u;
}

// ---------------- pack fp32 weight [L][K][N] -> bf16 B-frag layout [L][K0][N0][lane][8]
__global__ __launch_bounds__(256) void k_convw(const float* __restrict__ src,
    u16* __restrict__ dst, int K, int Kp, int N, int total)
{
  int idx = blockIdx.x*256 + threadIdx.x;
  if (idx >= total) return;
  int lane = idx & 63;
  int rest = idx >> 6;
  int Nt = N >> 4;
  int n0 = rest % Nt;
  int rest2 = rest / Nt;
  int Kt = Kp >> 5;
  int k0 = rest2 % Kt;
  int layer = rest2 / Kt;
  int kq = lane >> 4, nl = lane & 15;
  int kb = k0*32 + kq*8, n = n0*16 + nl;
  u16 o[8];
  #pragma unroll
  for (int j=0;j<8;j++){
    int k = kb + j;
    float v = (k < K) ? src[((size_t)layer*K + k)*N + n] : 0.f;
    o[j] = f2b(v);
  }
  *(uint4*)(dst + (size_t)idx*8) = *(uint4*)o;
}

// ---------------- feature embedding + coords ----------------
__global__ __launch_bounds__(256) void k_embed(
    const float* __restrict__ protPos, const int* __restrict__ protEle,
    const int* __restrict__ protAA, const int* __restrict__ protBB,
    const float* __restrict__ XtPos, const float* __restrict__ XtFeat,
    const int* __restrict__ tArr, const float* __restrict__ WtTime,
    const float* __restrict__ Wele, const float* __restrict__ Waa,
    const float* __restrict__ Wbb,
    float* __restrict__ feats, float* __restrict__ X0, float* __restrict__ X1)
{
  int i = blockIdx.x*256+threadIdx.x;
  if (i >= NTOT) return;
  float c0,c1,c2;
  float* f = feats + i*40;
  if (i < N_LIGC){
    c0 = XtPos[i*3+0]; c1 = XtPos[i*3+1]; c2 = XtPos[i*3+2];
    #pragma unroll
    for (int k=0;k<32;k++) f[k] = XtFeat[i*32+k];
    int tt = tArr[i];
    #pragma unroll
    for (int k=0;k<8;k++) f[32+k] = WtTime[tt*8+k];
  } else {
    int p = i - N_LIGC;
    c0 = protPos[p*3+0]; c1 = protPos[p*3+1]; c2 = protPos[p*3+2];
    int e = protEle[p], a = protAA[p], b = protBB[p];
    #pragma unroll
    for (int k=0;k<16;k++) f[k] = Wele[e*16+k];
    #pragma unroll
    for (int k=0;k<16;k++) f[16+k] = Waa[a*16+k];
    #pragma unroll
    for (int k=0;k<8;k++) f[32+k] = Wbb[b*8+k];
  }
  X0[i*3+0]=c0; X0[i*3+1]=c1; X0[i*3+2]=c2;
  X1[i*3+0]=c0; X1[i*3+1]=c1; X1[i*3+2]=c2;
}

// ---------------- h = feats @ W_in + b_in (fp32 + bf16 shadow) ----------------
__global__ __launch_bounds__(256) void k_hinit(const float* __restrict__ feats,
    const float* __restrict__ Win, const float* __restrict__ bin,
    float* __restrict__ h, u16* __restrict__ h_bf)
{
  __shared__ float sF[8*40];
  int blk=blockIdx.x, tid=threadIdx.x;
  int n0=blk*8;
  for (int x=tid;x<320;x+=256) sF[x]=feats[n0*40+x];
  __syncthreads();
  float acc[8];
  float b=bin[tid];
  #pragma unroll
  for (int n=0;n<8;n++) acc[n]=b;
  for (int k=0;k<40;k++){
    float w=Win[k*HID+tid];
    #pragma unroll
    for (int n=0;n<8;n++) acc[n]+=sF[n*40+k]*w;
  }
  #pragma unroll
  for (int n=0;n<8;n++){
    h[(size_t)(n0+n)*HID+tid]=acc[n];
    h_bf[(size_t)(n0+n)*HID+tid]=f2b(acc[n]);
  }
}

// ---------------- KNN: one block per ligand node ----------------
__global__ __launch_bounds__(256) void k_knn(const float* __restrict__ X,
    int* __restrict__ col, float* __restrict__ emb0)
{
  __shared__ float sd[NTOT];
  __shared__ float selD[KNN];
  __shared__ float rv[4];
  __shared__ int ri[4];
  int b = blockIdx.x, tid = threadIdx.x;
  float px = X[b*3+0], py = X[b*3+1], pz = X[b*3+2];
  for (int i=tid;i<NTOT;i+=256){
    float dx = px - X[i*3+0], dy = py - X[i*3+1], dz = pz - X[i*3+2];
    float d2 = dx*dx+dy*dy+dz*dz;
    sd[i] = (i==b) ? INFINITY : d2;
  }
  __syncthreads();
  for (int it=0; it<KNN; it++){
    float bv = INFINITY; int bi = 0x7fffffff;
    for (int i=tid;i<NTOT;i+=256){
      float v = sd[i];
      if (v < bv){ bv=v; bi=i; }
    }
    #pragma unroll
    for (int off=32; off>=1; off>>=1){
      float ov = __shfl_down(bv, off);
      int   oi = __shfl_down(bi, off);
      if (ov < bv || (ov==bv && oi<bi)){ bv=ov; bi=oi; }
    }
    if ((tid&63)==0){ rv[tid>>6]=bv; ri[tid>>6]=bi; }
    __syncthreads();
    if (tid==0){
      for (int w=1;w<4;w++){
        if (rv[w]<bv || (rv[w]==bv && ri[w]<bi)){ bv=rv[w]; bi=ri[w]; }
      }
      col[b*KNN+it] = bi;
      selD[it] = bv;
      sd[bi] = INFINITY;
    }
    __syncthreads();
  }
  if (tid < KNN){
    float d = sqrtf(selD[tid] + 1e-8f);
    int base = (b*KNN+tid)*12;
    #pragma unroll
    for (int i=0;i<6;i++){
      float fr = freq_f(i);
      emb0[base+i]   = sinf(d*fr);
      emb0[base+6+i] = cosf(d*fr);
    }
  }
}

// ---------------- edge MLP (MFMA) + attention + full-row aggregate ----------------
// one block per ligand row: M=48 edges, K=544 (pad), N=256
__global__ __launch_bounds__(256) void k_edge(
    const u16* __restrict__ h_bf, const float* __restrict__ xc,
    const int* __restrict__ colIdx, const float* __restrict__ emb0,
    const u16* __restrict__ W1p, const float* __restrict__ B1,
    const u16* __restrict__ W2p, const float* __restrict__ B2,
    const float* __restrict__ attW, const float* __restrict__ attB,
    u16* __restrict__ agg_bf, int l)
{
  __shared__ __align__(16) u16 sA[48*552];
  __shared__ __align__(16) u16 sM1[48*264];
  __shared__ int sCol[48];
  __shared__ float sSig[48];
  __shared__ float sDot[48][4];
  float* sM2 = (float*)sA;   // 48*264 fp32 = 50688 B <= 52992 B

  int blk = blockIdx.x, tid = threadIdx.x;
  int lane = tid & 63, wv = tid >> 6;
  int quad = lane >> 4, nl = lane & 15;

  if (tid < 48) sCol[tid] = colIdx[blk*KNN + tid];
  __syncthreads();
  for (int t = tid; t < 48*64; t += 256) {
    int e = t >> 6, q = t & 63;
    uint4 v;
    if (q < 32) v = ((const uint4*)(h_bf + (size_t)blk*HID))[q];
    else        v = ((const uint4*)(h_bf + (size_t)sCol[e]*HID))[q-32];
    *(uint4*)(sA + e*552 + q*8) = v;
  }
  if (tid < 48) {
    int cg = sCol[tid];
    float dx = xc[blk*3+0]-xc[cg*3+0];
    float dy = xc[blk*3+1]-xc[cg*3+1];
    float dz = xc[blk*3+2]-xc[cg*3+2];
    float d = sqrtf(dx*dx+dy*dy+dz*dz + 1e-8f);
    u16* ea = sA + tid*552 + 512;
    #pragma unroll
    for (int i=0;i<6;i++){
      float fr = freq_f(i);
      ea[i]   = f2b(sinf(d*fr));
      ea[6+i] = f2b(cosf(d*fr));
    }
    #pragma unroll
    for (int i=0;i<12;i++) ea[12+i] = f2b(emb0[(size_t)(blk*KNN+tid)*12 + i]);
    #pragma unroll
    for (int i=24;i<32;i++) ea[i] = 0;
  }
  __syncthreads();

  f32x4 zero4 = {0.f,0.f,0.f,0.f};
  f32x4 acc[3][4];
  #pragma unroll
  for (int i=0;i<3;i++){ acc[i][0]=zero4; acc[i][1]=zero4; acc[i][2]=zero4; acc[i][3]=zero4; }
  const u16* Wp = W1p + (size_t)l*544*HID;
  #pragma unroll 2
  for (int k0=0;k0<17;k0++){
    bf16x8 a0 = *(const bf16x8*)(sA + (0*16+nl)*552 + k0*32 + quad*8);
    bf16x8 a1 = *(const bf16x8*)(sA + (1*16+nl)*552 + k0*32 + quad*8);
    bf16x8 a2 = *(const bf16x8*)(sA + (2*16+nl)*552 + k0*32 + quad*8);
    const u16* wb = Wp + ((size_t)(k0*16 + wv*4)*64 + lane)*8;
    bf16x8 b0 = *(const bf16x8*)(wb);
    bf16x8 b1 = *(const bf16x8*)(wb + 512);
    bf16x8 b2 = *(const bf16x8*)(wb + 1024);
    bf16x8 b3 = *(const bf16x8*)(wb + 1536);
    acc[0][0]=__builtin_amdgcn_mfma_f32_16x16x32_bf16(a0,b0,acc[0][0],0,0,0);
    acc[0][1]=__builtin_amdgcn_mfma_f32_16x16x32_bf16(a0,b1,acc[0][1],0,0,0);
    acc[0][2]=__builtin_amdgcn_mfma_f32_16x16x32_bf16(a0,b2,acc[0][2],0,0,0);
    acc[0][3]=__builtin_amdgcn_mfma_f32_16x16x32_bf16(a0,b3,acc[0][3],0,0,0);
    acc[1][0]=__builtin_amdgcn_mfma_f32_16x16x32_bf16(a1,b0,acc[1][0],0,0,0);
    acc[1][1]=__builtin_amdgcn_mfma_f32_16x16x32_bf16(a1,b1,acc[1][1],0,0,0);
    acc[1][2]=__builtin_amdgcn_mfma_f32_16x16x32_bf16(a1,b2,acc[1][2],0,0,0);
    acc[1][3]=__builtin_amdgcn_mfma_f32_16x16x32_bf16(a1,b3,acc[1][3],0,0,0);
    acc[2][0]=__builtin_amdgcn_mfma_f32_16x16x32_bf16(a2,b0,acc[2][0],0,0,0);
    acc[2][1]=__builtin_amdgcn_mfma_f32_16x16x32_bf16(a2,b1,acc[2][1],0,0,0);
    acc[2][2]=__builtin_amdgcn_mfma_f32_16x16x32_bf16(a2,b2,acc[2][2],0,0,0);
    acc[2][3]=__builtin_amdgcn_mfma_f32_16x16x32_bf16(a2,b3,acc[2][3],0,0,0);
  }
  #pragma unroll
  for (int mt=0;mt<3;mt++)
  #pragma unroll
  for (int nt=0;nt<4;nt++){
    int n = wv*64 + nt*16 + nl;
    float bb = B1[l*HID + n];
    #pragma unroll
    for (int r=0;r<4;r++){
      int m = mt*16 + quad*4 + r;
      sM1[m*264 + n] = f2b(silu_f(acc[mt][nt][r] + bb));
    }
  }
  __syncthreads();

  f32x4 acc2[3][4];
  #pragma unroll
  for (int i=0;i<3;i++){ acc2[i][0]=zero4; acc2[i][1]=zero4; acc2[i][2]=zero4; acc2[i][3]=zero4; }
  const u16* W2 = W2p + (size_t)l*HID*HID;
  #pragma unroll 2
  for (int k0=0;k0<8;k0++){
    bf16x8 a0 = *(const bf16x8*)(sM1 + (0*16+nl)*264 + k0*32 + quad*8);
    bf16x8 a1 = *(const bf16x8*)(sM1 + (1*16+nl)*264 + k0*32 + quad*8);
    bf16x8 a2 = *(const bf16x8*)(sM1 + (2*16+nl)*264 + k0*32 + quad*8);
    const u16* wb = W2 + ((size_t)(k0*16 + wv*4)*64 + lane)*8;
    bf16x8 b0 = *(const bf16x8*)(wb);
    bf16x8 b1 = *(const bf16x8*)(wb + 512);
    bf16x8 b2 = *(const bf16x8*)(wb + 1024);
    bf16x8 b3 = *(const bf16x8*)(wb + 1536);
    acc2[0][0]=__builtin_amdgcn_mfma_f32_16x16x32_bf16(a0,b0,acc2[0][0],0,0,0);
    acc2[0][1]=__builtin_amdgcn_mfma_f32_16x16x32_bf16(a0,b1,acc2[0][1],0,0,0);
    acc2[0][2]=__builtin_amdgcn_mfma_f32_16x16x32_bf16(a0,b2,acc2[0][2],0,0,0);
    acc2[0][3]=__builtin_amdgcn_mfma_f32_16x16x32_bf16(a0,b3,acc2[0][3],0,0,0);
    acc2[1][0]=__builtin_amdgcn_mfma_f32_16x16x32_bf16(a1,b0,acc2[1][0],0,0,0);
    acc2[1][1]=__builtin_amdgcn_mfma_f32_16x16x32_bf16(a1,b1,acc2[1][1],0,0,0);
    acc2[1][2]=__builtin_amdgcn_mfma_f32_16x16x32_bf16(a1,b2,acc2[1][2],0,0,0);
    acc2[1][3]=__builtin_amdgcn_mfma_f32_16x16x32_bf16(a1,b3,acc2[1][3],0,0,0);
    acc2[2][0]=__builtin_amdgcn_mfma_f32_16x16x32_bf16(a2,b0,acc2[2][0],0,0,0);
    acc2[2][1]=__builtin_amdgcn_mfma_f32_16x16x32_bf16(a2,b1,acc2[2][1],0,0,0);
    acc2[2][2]=__builtin_amdgcn_mfma_f32_16x16x32_bf16(a2,b2,acc2[2][2],0,0,0);
    acc2[2][3]=__builtin_amdgcn_mfma_f32_16x16x32_bf16(a2,b3,acc2[2][3],0,0,0);
  }
  __syncthreads();   // done reading sA(stage1) & sM1 -> safe to overwrite sM2 alias
  #pragma unroll
  for (int mt=0;mt<3;mt++)
  #pragma unroll
  for (int nt=0;nt<4;nt++){
    int n = wv*64 + nt*16 + nl;
    float bb = B2[l*HID + n];
    #pragma unroll
    for (int r=0;r<4;r++){
      int m = mt*16 + quad*4 + r;
      sM2[m*264 + n] = silu_f(acc2[mt][nt][r] + bb);
    }
  }
  __syncthreads();
  {
    int e = tid >> 2, qq = tid & 3;
    if (e < 48){
      float s = 0.f; int nb = qq*64;
      #pragma unroll 4
      for (int n=0;n<64;n++) s += sM2[e*264 + nb + n]*attW[l*HID + nb + n];
      sDot[e][qq] = s;
    }
  }
  __syncthreads();
  if (tid < 48){
    float s = sDot[tid][0]+sDot[tid][1]+sDot[tid][2]+sDot[tid][3] + attB[l];
    sSig[tid] = 1.f/(1.f+expf(-s));
  }
  __syncthreads();
  {
    float a = 0.f;
    #pragma unroll 4
    for (int e=0;e<48;e++) a += sM2[e*264 + tid]*sSig[e];
    agg_bf[(size_t)blk*HID + tid] = f2b(a/5.0f);
  }
}

// ---------------- node MLP (MFMA, residual): 32 nodes/block ----------------
__global__ __launch_bounds__(256) void k_node(
    float* __restrict__ h, u16* __restrict__ h_bf,
    const u16* __restrict__ agg_bf,
    const u16* __restrict__ W1p, const float* __restrict__ B1,
    const u16* __restrict__ W2p, const float* __restrict__ B2, int l)
{
  __shared__ __align__(16) u16 sA[32*520];
  __shared__ __align__(16) u16 sU[32*264];
  int blk=blockIdx.x, tid=threadIdx.x;
  int lane=tid&63, wv=tid>>6, quad=lane>>4, nl=lane&15;
  for (int t=tid; t<32*64; t+=256){
    int i=t>>6, q=t&63;
    int node = blk*32+i;
    uint4 v;
    if (q<32) v = ((const uint4*)(h_bf + (size_t)node*HID))[q];
    else if (node < N_LIGC) v = ((const uint4*)(agg_bf + (size_t)node*HID))[q-32];
    else { v.x=0u; v.y=0u; v.z=0u; v.w=0u; }
    *(uint4*)(sA + i*520 + q*8) = v;
  }
  __syncthreads();
  f32x4 zero4 = {0.f,0.f,0.f,0.f};
  f32x4 acc[2][4];
  #pragma unroll
  for (int i=0;i<2;i++){ acc[i][0]=zero4; acc[i][1]=zero4; acc[i][2]=zero4; acc[i][3]=zero4; }
  const u16* Wp = W1p + (size_t)l*512*HID;
  #pragma unroll 2
  for (int k0=0;k0<16;k0++){
    bf16x8 a0 = *(const bf16x8*)(sA + (0*16+nl)*520 + k0*32 + quad*8);
    bf16x8 a1 = *(const bf16x8*)(sA + (1*16+nl)*520 + k0*32 + quad*8);
    const u16* wb = Wp + ((size_t)(k0*16 + wv*4)*64 + lane)*8;
    bf16x8 b0 = *(const bf16x8*)(wb);
    bf16x8 b1 = *(const bf16x8*)(wb + 512);
    bf16x8 b2 = *(const bf16x8*)(wb + 1024);
    bf16x8 b3 = *(const bf16x8*)(wb + 1536);
    acc[0][0]=__builtin_amdgcn_mfma_f32_16x16x32_bf16(a0,b0,acc[0][0],0,0,0);
    acc[0][1]=__builtin_amdgcn_mfma_f32_16x16x32_bf16(a0,b1,acc[0][1],0,0,0);
    acc[0][2]=__builtin_amdgcn_mfma_f32_16x16x32_bf16(a0,b2,acc[0][2],0,0,0);
    acc[0][3]=__builtin_amdgcn_mfma_f32_16x16x32_bf16(a0,b3,acc[0][3],0,0,0);
    acc[1][0]=__builtin_amdgcn_mfma_f32_16x16x32_bf16(a1,b0,acc[1][0],0,0,0);
    acc[1][1]=__builtin_amdgcn_mfma_f32_16x16x32_bf16(a1,b1,acc[1][1],0,0,0);
    acc[1][2]=__builtin_amdgcn_mfma_f32_16x16x32_bf16(a1,b2,acc[1][2],0,0,0);
    acc[1][3]=__builtin_amdgcn_mfma_f32_16x16x32_bf16(a1,b3,acc[1][3],0,0,0);
  }
  #pragma unroll
  for (int mt=0;mt<2;mt++)
  #pragma unroll
  for (int nt=0;nt<4;nt++){
    int n = wv*64 + nt*16 + nl;
    float bb = B1[l*HID + n];
    #pragma unroll
    for (int r=0;r<4;r++){
      int m = mt*16 + quad*4 + r;
      sU[m*264 + n] = f2b(silu_f(acc[mt][nt][r] + bb));
    }
  }
  __syncthreads();
  f32x4 acc2[2][4];
  #pragma unroll
  for (int i=0;i<2;i++){ acc2[i][0]=zero4; acc2[i][1]=zero4; acc2[i][2]=zero4; acc2[i][3]=zero4; }
  const u16* W2 = W2p + (size_t)l*HID*HID;
  #pragma unroll 2
  for (int k0=0;k0<8;k0++){
    bf16x8 a0 = *(const bf16x8*)(sU + (0*16+nl)*264 + k0*32 + quad*8);
    bf16x8 a1 = *(const bf16x8*)(sU + (1*16+nl)*264 + k0*32 + quad*8);
    const u16* wb = W2 + ((size_t)(k0*16 + wv*4)*64 + lane)*8;
    bf16x8 b0 = *(const bf16x8*)(wb);
    bf16x8 b1 = *(const bf16x8*)(wb + 512);
    bf16x8 b2 = *(const bf16x8*)(wb + 1024);
    bf16x8 b3 = *(const bf16x8*)(wb + 1536);
    acc2[0][0]=__builtin_amdgcn_mfma_f32_16x16x32_bf16(a0,b0,acc2[0][0],0,0,0);
    acc2[0][1]=__builtin_amdgcn_mfma_f32_16x16x32_bf16(a0,b1,acc2[0][1],0,0,0);
    acc2[0][2]=__builtin_amdgcn_mfma_f32_16x16x32_bf16(a0,b2,acc2[0][2],0,0,0);
    acc2[0][3]=__builtin_amdgcn_mfma_f32_16x16x32_bf16(a0,b3,acc2[0][3],0,0,0);
    acc2[1][0]=__builtin_amdgcn_mfma_f32_16x16x32_bf16(a1,b0,acc2[1][0],0,0,0);
    acc2[1][1]=__builtin_amdgcn_mfma_f32_16x16x32_bf16(a1,b1,acc2[1][1],0,0,0);
    acc2[1][2]=__builtin_amdgcn_mfma_f32_16x16x32_bf16(a1,b2,acc2[1][2],0,0,0);
    acc2[1][3]=__builtin_amdgcn_mfma_f32_16x16x32_bf16(a1,b3,acc2[1][3],0,0,0);
  }
  #pragma unroll
  for (int mt=0;mt<2;mt++)
  #pragma unroll
  for (int nt=0;nt<4;nt++){
    int n = wv*64 + nt*16 + nl;
    float bb = B2[l*HID + n];
    #pragma unroll
    for (int r=0;r<4;r++){
      int m = mt*16 + quad*4 + r;
      size_t idx = (size_t)(blk*32+m)*HID + n;
      float v = h[idx] + acc2[mt][nt][r] + bb;
      h[idx] = v;
      h_bf[idx] = f2b(v);
    }
  }
}

// ---------------- coord MLP (MFMA, uses UPDATED h) + x update ----------------
__global__ __launch_bounds__(256) void k_coord(
    const u16* __restrict__ h_bf, const float* __restrict__ xc,
    float* __restrict__ xn,
    const int* __restrict__ colIdx, const float* __restrict__ emb0,
    const u16* __restrict__ W1p, const float* __restrict__ B1,
    const u16* __restrict__ W2p, const float* __restrict__ B2,
    const float* __restrict__ cW3, int l)
{
  __shared__ __align__(16) u16 sA[48*552];
  __shared__ __align__(16) u16 sM1[48*264];
  __shared__ int sCol[48];
  __shared__ float sCd[48*3];
  __shared__ float sS[48];
  __shared__ float sDot[48][4];
  float* sM2 = (float*)sA;

  int blk = blockIdx.x, tid = threadIdx.x;
  int lane = tid & 63, wv = tid >> 6;
  int quad = lane >> 4, nl = lane & 15;

  if (tid < 48) sCol[tid] = colIdx[blk*KNN + tid];
  __syncthreads();
  for (int t = tid; t < 48*64; t += 256) {
    int e = t >> 6, q = t & 63;
    uint4 v;
    if (q < 32) v = ((const uint4*)(h_bf + (size_t)blk*HID))[q];
    else        v = ((const uint4*)(h_bf + (size_t)sCol[e]*HID))[q-32];
    *(uint4*)(sA + e*552 + q*8) = v;
  }
  if (tid < 48) {
    int cg = sCol[tid];
    float dx = xc[blk*3+0]-xc[cg*3+0];
    float dy = xc[blk*3+1]-xc[cg*3+1];
    float dz = xc[blk*3+2]-xc[cg*3+2];
    float d = sqrtf(dx*dx+dy*dy+dz*dz + 1e-8f);
    float den = d + 1.0f;
    sCd[tid*3+0]=dx/den; sCd[tid*3+1]=dy/den; sCd[tid*3+2]=dz/den;
    u16* ea = sA + tid*552 + 512;
    #pragma unroll
    for (int i=0;i<6;i++){
      float fr = freq_f(i);
      ea[i]   = f2b(sinf(d*fr));
      ea[6+i] = f2b(cosf(d*fr));
    }
    #pragma unroll
    for (int i=0;i<12;i++) ea[12+i] = f2b(emb0[(size_t)(blk*KNN+tid)*12 + i]);
    #pragma unroll
    for (int i=24;i<32;i++) ea[i] = 0;
  }
  __syncthreads();

  f32x4 zero4 = {0.f,0.f,0.f,0.f};
  f32x4 acc[3][4];
  #pragma unroll
  for (int i=0;i<3;i++){ acc[i][0]=zero4; acc[i][1]=zero4; acc[i][2]=zero4; acc[i][3]=zero4; }
  const u16* Wp = W1p + (size_t)l*544*HID;
  #pragma unroll 2
  for (int k0=0;k0<17;k0++){
    bf16x8 a0 = *(const bf16x8*)(sA + (0*16+nl)*552 + k0*32 + quad*8);
    bf16x8 a1 = *(const bf16x8*)(sA + (1*16+nl)*552 + k0*32 + quad*8);
    bf16x8 a2 = *(const bf16x8*)(sA + (2*16+nl)*552 + k0*32 + quad*8);
    const u16* wb = Wp + ((size_t)(k0*16 + wv*4)*64 + lane)*8;
    bf16x8 b0 = *(const bf16x8*)(wb);
    bf16x8 b1 = *(const bf16x8*)(wb + 512);
    bf16x8 b2 = *(const bf16x8*)(wb + 1024);
    bf16x8 b3 = *(const bf16x8*)(wb + 1536);
    acc[0][0]=__builtin_amdgcn_mfma_f32_16x16x32_bf16(a0,b0,acc[0][0],0,0,0);
    acc[0][1]=__builtin_amdgcn_mfma_f32_16x16x32_bf16(a0,b1,acc[0][1],0,0,0);
    acc[0][2]=__builtin_amdgcn_mfma_f32_16x16x32_bf16(a0,b2,acc[0][2],0,0,0);
    acc[0][3]=__builtin_amdgcn_mfma_f32_16x16x32_bf16(a0,b3,acc[0][3],0,0,0);
    acc[1][0]=__builtin_amdgcn_mfma_f32_16x16x32_bf16(a1,b0,acc[1][0],0,0,0);
    acc[1][1]=__builtin_amdgcn_mfma_f32_16x16x32_bf16(a1,b1,acc[1][1],0,0,0);
    acc[1][2]=__builtin_amdgcn_mfma_f32_16x16x32_bf16(a1,b2,acc[1][2],0,0,0);
    acc[1][3]=__builtin_amdgcn_mfma_f32_16x16x32_bf16(a1,b3,acc[1][3],0,0,0);
    acc[2][0]=__builtin_amdgcn_mfma_f32_16x16x32_bf16(a2,b0,acc[2][0],0,0,0);
    acc[2][1]=__builtin_amdgcn_mfma_f32_16x16x32_bf16(a2,b1,acc[2][1],0,0,0);
    acc[2][2]=__builtin_amdgcn_mfma_f32_16x16x32_bf16(a2,b2,acc[2][2],0,0,0);
    acc[2][3]=__builtin_amdgcn_mfma_f32_16x16x32_bf16(a2,b3,acc[2][3],0,0,0);
  }
  #pragma unroll
  for (int mt=0;mt<3;mt++)
  #pragma unroll
  for (int nt=0;nt<4;nt++){
    int n = wv*64 + nt*16 + nl;
    float bb = B1[l*HID + n];
    #pragma unroll
    for (int r=0;r<4;r++){
      int m = mt*16 + quad*4 + r;
      sM1[m*264 + n] = f2b(silu_f(acc[mt][nt][r] + bb));
    }
  }
  __syncthreads();

  f32x4 acc2[3][4];
  #pragma unroll
  for (int i=0;i<3;i++){ acc2[i][0]=zero4; acc2[i][1]=zero4; acc2[i][2]=zero4; acc2[i][3]=zero4; }
  const u16* W2 = W2p + (size_t)l*HID*HID;
  #pragma unroll 2
  for (int k0=0;k0<8;k0++){
    bf16x8 a0 = *(const bf16x8*)(sM1 + (0*16+nl)*264 + k0*32 + quad*8);
    bf16x8 a1 = *(const bf16x8*)(sM1 + (1*16+nl)*264 + k0*32 + quad*8);
    bf16x8 a2 = *(const bf16x8*)(sM1 + (2*16+nl)*264 + k0*32 + quad*8);
    const u16* wb = W2 + ((size_t)(k0*16 + wv*4)*64 + lane)*8;
    bf16x8 b0 = *(const bf16x8*)(wb);
    bf16x8 b1 = *(const bf16x8*)(wb + 512);
    bf16x8 b2 = *(const bf16x8*)(wb + 1024);
    bf16x8 b3 = *(const bf16x8*)(wb + 1536);
    acc2[0][0]=__builtin_amdgcn_mfma_f32_16x16x32_bf16(a0,b0,acc2[0][0],0,0,0);
    acc2[0][1]=__builtin_amdgcn_mfma_f32_16x16x32_bf16(a0,b1,acc2[0][1],0,0,0);
    acc2[0][2]=__builtin_amdgcn_mfma_f32_16x16x32_bf16(a0,b2,acc2[0][2],0,0,0);
    acc2[0][3]=__builtin_amdgcn_mfma_f32_16x16x32_bf16(a0,b3,acc2[0][3],0,0,0);
    acc2[1][0]=__builtin_amdgcn_mfma_f32_16x16x32_bf16(a1,b0,acc2[1][0],0,0,0);
    acc2[1][1]=__builtin_amdgcn_mfma_f32_16x16x32_bf16(a1,b1,acc2[1][1],0,0,0);
    acc2[1][2]=__builtin_amdgcn_mfma_f32_16x16x32_bf16(a1,b2,acc2[1][2],0,0,0);
    acc2[1][3]=__builtin_amdgcn_mfma_f32_16x16x32_bf16(a1,b3,acc2[1][3],0,0,0);
    acc2[2][0]=__builtin_amdgcn_mfma_f32_16x16x32_bf16(a2,b0,acc2[2][0],0,0,0);
    acc2[2][1]=__builtin_amdgcn_mfma_f32_16x16x32_bf16(a2,b1,acc2[2][1],0,0,0);
    acc2[2][2]=__builtin_amdgcn_mfma_f32_16x16x32_bf16(a2,b2,acc2[2][2],0,0,0);
    acc2[2][3]=__builtin_amdgcn_mfma_f32_16x16x32_bf16(a2,b3,acc2[2][3],0,0,0);
  }
  __syncthreads();
  #pragma unroll
  for (int mt=0;mt<3;mt++)
  #pragma unroll
  for (int nt=0;nt<4;nt++){
    int n = wv*64 + nt*16 + nl;
    float bb = B2[l*HID + n];
    #pragma unroll
    for (int r=0;r<4;r++){
      int m = mt*16 + quad*4 + r;
      sM2[m*264 + n] = silu_f(acc2[mt][nt][r] + bb);
    }
  }
  __syncthreads();
  {
    int e = tid >> 2, qq = tid & 3;
    if (e < 48){
      float s = 0.f; int nb = qq*64;
      #pragma unroll 4
      for (int n=0;n<64;n++) s += sM2[e*264 + nb + n]*cW3[l*HID + nb + n];
      sDot[e][qq] = s;
    }
  }
  __syncthreads();
  if (tid < 48) sS[tid] = sDot[tid][0]+sDot[tid][1]+sDot[tid][2]+sDot[tid][3];
  __syncthreads();
  if (tid < 3){
    float u = 0.f;
    #pragma unroll 4
    for (int e=0;e<48;e++) u += sCd[e*3+tid]*sS[e];
    xn[blk*3+tid] = xc[blk*3+tid] + u/5.0f;
  }
}

// ---------------- outputs ----------------
__global__ void k_outx(const float* __restrict__ x, const float* __restrict__ posw,
                       float* __restrict__ out)
{
  int i=blockIdx.x*1024+threadIdx.x;
  if (i<3072) out[i]=x[i]*posw[0];
}

__global__ __launch_bounds__(256) void k_outh(const float* __restrict__ h,
    const float* __restrict__ Wout, const float* __restrict__ bout,
    float* __restrict__ out)
{
  __shared__ float sH[2048];
  int blk=blockIdx.x, tid=threadIdx.x;
  int n0=blk*8;
  for (int x=tid;x<2048;x+=256) sH[x]=h[(size_t)n0*HID+x];
  __syncthreads();
  int nl=tid>>5, j=tid&31;
  float acc=bout[j];
  #pragma unroll 4
  for (int k=0;k<256;k++) acc += sH[nl*HID+k]*Wout[k*32+j];
  out[3072 + (n0+nl)*32 + j]=acc;
}

extern "C" void kernel_launch(void* const* d_in, const int* in_sizes, int n_in,
                              void* d_out, int out_size, void* d_ws, size_t ws_size,
                              hipStream_t stream)
{
  const float* protPos = (const float*)d_in[0];
  const int*   protEle = (const int*)d_in[1];
  const int*   protAA  = (const int*)d_in[2];
  const int*   protBB  = (const int*)d_in[3];
  const float* XtPos   = (const float*)d_in[4];
  const float* XtFeat  = (const float*)d_in[5];
  const int*   tArr    = (const int*)d_in[6];
  const float* WtTime  = (const float*)d_in[7];
  const float* Wele    = (const float*)d_in[8];
  const float* Waa     = (const float*)d_in[9];
  const float* Wbb     = (const float*)d_in[10];
  const float* Win     = (const float*)d_in[11];
  const float* bin     = (const float*)d_in[12];
  const float* Wout    = (const float*)d_in[13];
  const float* bout    = (const float*)d_in[14];
  const float* eW1     = (const float*)d_in[15];
  const float* eB1     = (const float*)d_in[16];
  const float* eW2     = (const float*)d_in[17];
  const float* eB2     = (const float*)d_in[18];
  const float* attW    = (const float*)d_in[19];
  const float* attB    = (const float*)d_in[20];
  const float* nW1     = (const float*)d_in[21];
  const float* nB1     = (const float*)d_in[22];
  const float* nW2     = (const float*)d_in[23];
  const float* nB2     = (const float*)d_in[24];
  const float* cW1     = (const float*)d_in[25];
  const float* cB1     = (const float*)d_in[26];
  const float* cW2     = (const float*)d_in[27];
  const float* cB2     = (const float*)d_in[28];
  const float* cW3     = (const float*)d_in[29];
  const float* posw    = (const float*)d_in[30];

  float* fp = (float*)d_ws;
  float* X0   = fp;               fp += NTOT*3;
  float* X1   = fp;               fp += NTOT*3;
  float* feats= fp;               fp += NTOT*40;
  float* h    = fp;               fp += (size_t)NTOT*HID;
  float* emb0 = fp;               fp += (size_t)ETOT*12;
  int*   col  = (int*)fp;         fp += ETOT;
  u16*   up   = (u16*)fp;
  u16* h_bf   = up;               up += (size_t)NTOT*HID;
  u16* agg_bf = up;               up += (size_t)N_LIGC*HID;
  u16* eW1p   = up;               up += (size_t)DEPTHC*544*HID;
  u16* eW2p   = up;               up += (size_t)DEPTHC*HID*HID;
  u16* nW1p   = up;               up += (size_t)DEPTHC*512*HID;
  u16* nW2p   = up;               up += (size_t)DEPTHC*HID*HID;
  u16* cW1p   = up;               up += (size_t)DEPTHC*544*HID;
  u16* cW2p   = up;               up += (size_t)DEPTHC*HID*HID;

  // weight packing (once per launch; same work every call)
  {
    int t1 = DEPTHC*544*HID/8;  // 87040
    int t2 = DEPTHC*HID*HID/8;  // 40960
    int t3 = DEPTHC*512*HID/8;  // 81920
    k_convw<<<(t1+255)/256,256,0,stream>>>(eW1, eW1p, 536, 544, HID, t1);
    k_convw<<<(t2+255)/256,256,0,stream>>>(eW2, eW2p, 256, 256, HID, t2);
    k_convw<<<(t3+255)/256,256,0,stream>>>(nW1, nW1p, 512, 512, HID, t3);
    k_convw<<<(t2+255)/256,256,0,stream>>>(nW2, nW2p, 256, 256, HID, t2);
    k_convw<<<(t1+255)/256,256,0,stream>>>(cW1, cW1p, 536, 544, HID, t1);
    k_convw<<<(t2+255)/256,256,0,stream>>>(cW2, cW2p, 256, 256, HID, t2);
  }

  k_embed<<<36,256,0,stream>>>(protPos,protEle,protAA,protBB,XtPos,XtFeat,tArr,
                               WtTime,Wele,Waa,Wbb,feats,X0,X1);
  k_hinit<<<NTOT/8,256,0,stream>>>(feats,Win,bin,h,h_bf);
  k_knn<<<N_LIGC,256,0,stream>>>(X0,col,emb0);

  float* xc = X0; float* xn = X1;
  for (int l=0;l<DEPTHC;l++){
    k_edge<<<N_LIGC,256,0,stream>>>(h_bf,xc,col,emb0,eW1p,eB1,eW2p,eB2,attW,attB,agg_bf,l);
    k_node<<<NTOT/32,256,0,stream>>>(h,h_bf,agg_bf,nW1p,nB1,nW2p,nB2,l);
    k_coord<<<N_LIGC,256,0,stream>>>(h_bf,xc,xn,col,emb0,cW1p,cB1,cW2p,cB2,cW3,l);
    float* t2=xc; xc=xn; xn=t2;
  }
  k_outx<<<3,1024,0,stream>>>(xc,posw,(float*)d_out);
  k_outh<<<N_LIGC/8,256,0,stream>>>(h,Wout,bout,(float*)d_out);
}